// Round 2
// baseline (53.771 us; speedup 1.0000x reference)
//
#include <hip/hip_runtime.h>
#include <stdint.h>

#define NROW 524288
#define BLK  256
#define NKNN 10
#define YCOLS 44
#define OCOLS 24   // dxdt(2) + dvdt(2) + dudt(20)

// LDS weight layout (float offsets)
#define O_W1A 0      // 32
#define O_B1A 32     // 8
#define O_W1B 40     // 16
#define O_B1B 56     // 2
#define O_W2A 64     // 16
#define O_B2A 80     // 16
#define O_W2B 96     // 128
#define O_B2B 224    // 8
#define O_W2C 232    // 8
#define O_B2C 240    // 1
#define O_W3A 256    // 16
#define O_B3A 272    // 16
#define O_W3B 288    // 128
#define O_B3B 416    // 8
#define O_W3C 424    // 8
#define O_B3C 432    // 1
#define WTOT  448

// scalar -> 16 -> 8 -> 1 MLP, weights in LDS (wave-uniform broadcast reads)
__device__ __forceinline__ float mlp_scalar(float s, const float* __restrict__ W,
                                            int wa, int ba, int wb, int bb, int wc, int bc) {
    float h[16];
#pragma unroll
    for (int j = 0; j < 16; ++j)
        h[j] = fmaxf(fmaf(s, W[wa + j], W[ba + j]), 0.0f);
    float g[8];
#pragma unroll
    for (int k = 0; k < 8; ++k) g[k] = W[bb + k];
#pragma unroll
    for (int j = 0; j < 16; ++j) {
        float hj = h[j];
#pragma unroll
        for (int k = 0; k < 8; ++k)
            g[k] = fmaf(hj, W[wb + j * 8 + k], g[k]);
    }
    float o = W[bc];
#pragma unroll
    for (int k = 0; k < 8; ++k)
        o = fmaf(fmaxf(g[k], 0.0f), W[wc + k], o);
    return o;
}

__global__ __launch_bounds__(BLK) void odefunc_kernel(
    const float* __restrict__ y,
    const float* __restrict__ w1a, const float* __restrict__ b1a,
    const float* __restrict__ w1b, const float* __restrict__ b1b,
    const float* __restrict__ w2a, const float* __restrict__ b2a,
    const float* __restrict__ w2b, const float* __restrict__ b2b,
    const float* __restrict__ w2c, const float* __restrict__ b2c,
    const float* __restrict__ w3a, const float* __restrict__ b3a,
    const float* __restrict__ w3b, const float* __restrict__ b3b,
    const float* __restrict__ w3c, const float* __restrict__ b3c,
    float* __restrict__ out)
{
    __shared__ float W[WTOT];
    __shared__ float4 outs[BLK];

    const int t = threadIdx.x;
    if (t < 32)  W[O_W1A + t] = w1a[t];
    if (t < 8)   W[O_B1A + t] = b1a[t];
    if (t < 16)  W[O_W1B + t] = w1b[t];
    if (t < 2)   W[O_B1B + t] = b1b[t];
    if (t < 16)  W[O_W2A + t] = w2a[t];
    if (t < 16)  W[O_B2A + t] = b2a[t];
    if (t < 128) W[O_W2B + t] = w2b[t];
    if (t < 8)   W[O_B2B + t] = b2b[t];
    if (t < 8)   W[O_W2C + t] = w2c[t];
    if (t < 1)   W[O_B2C + t] = b2c[t];
    if (t < 16)  W[O_W3A + t] = w3a[t];
    if (t < 16)  W[O_B3A + t] = b3a[t];
    if (t < 128) W[O_W3B + t] = w3b[t];
    if (t < 8)   W[O_B3B + t] = b3b[t];
    if (t < 8)   W[O_W3C + t] = w3c[t];
    if (t < 1)   W[O_B3C + t] = b3c[t];
    __syncthreads();

    const int row = blockIdx.x * BLK + t;
    // y row = 44 floats = 176 B = 11 * 16 B -> 16B-aligned row starts
    const float4* yr = reinterpret_cast<const float4*>(y + (size_t)row * YCOLS);
    float4 a  = yr[0];            // x0, x1, vx, vy
    float4 u0 = yr[1];
    float4 u1 = yr[2];
    float4 u2 = yr[3];
    float4 u3 = yr[4];
    float4 u4 = yr[5];            // cols 4..23 = ux[10][2]

    // ---- f1: door-direction MLP (4 -> 8 -> 2) ----
    float dx = 5.6f - a.x;
    float dy = 0.0f - a.y;
    float inv = rsqrtf(fmaf(dx, dx, dy * dy));
    float in1[4] = { dx * inv, dy * inv, a.z, a.w };
    float h1[8];
#pragma unroll
    for (int j = 0; j < 8; ++j) {
        float s = W[O_B1A + j];
#pragma unroll
        for (int k = 0; k < 4; ++k)
            s = fmaf(in1[k], W[O_W1A + k * 8 + j], s);
        h1[j] = fmaxf(s, 0.0f);
    }
    float f1x = W[O_B1B + 0];
    float f1y = W[O_B1B + 1];
#pragma unroll
    for (int j = 0; j < 8; ++j) {
        f1x = fmaf(h1[j], W[O_W1B + j * 2 + 0], f1x);
        f1y = fmaf(h1[j], W[O_W1B + j * 2 + 1], f1y);
    }

    // ---- f2: wall MLP on 4 scalar distances ----
    float rightdist = (a.y < 1.0f && a.y > -1.0f) ? 100.0f : (5.0f - a.x);
    float sw[4] = { a.x + 5.0f, a.y + 5.0f, 5.0f - a.y, rightdist };
    float o[4];
#pragma unroll
    for (int w = 0; w < 4; ++w)
        o[w] = mlp_scalar(sw[w], W, O_W2A, O_B2A, O_W2B, O_B2B, O_W2C, O_B2C);
    float f2x = o[0] - o[3];
    float f2y = o[1] - o[2];

    // ---- f3: neighbor MLP over 10 (ux,uy) pairs ----
    float us[2 * NKNN] = { u0.x, u0.y, u0.z, u0.w,
                           u1.x, u1.y, u1.z, u1.w,
                           u2.x, u2.y, u2.z, u2.w,
                           u3.x, u3.y, u3.z, u3.w,
                           u4.x, u4.y, u4.z, u4.w };
    float f3x = 0.0f, f3y = 0.0f;
#pragma unroll
    for (int n = 0; n < NKNN; ++n) {
        float uxn = us[2 * n + 0];
        float uyn = us[2 * n + 1];
        float s2  = fmaf(uxn, uxn, uyn * uyn);
        float idn = rsqrtf(s2);
        float d   = s2 * idn;     // = sqrt(s2)
        float m   = mlp_scalar(d, W, O_W3A, O_B3A, O_W3B, O_B3B, O_W3C, O_B3C);
        float c   = m * idn;
        f3x = fmaf(-c, uxn, f3x);
        f3y = fmaf(-c, uyn, f3y);
    }

    // ---- combine + mask ----
    bool dead = (a.x > 5.0f);
    const float k80 = 1.0f / 80.0f;
    float4 r;
    r.x = dead ? 0.0f : a.z;
    r.y = dead ? 0.0f : a.w;
    r.z = dead ? 0.0f : (f1x + f2x + f3x) * k80;
    r.w = dead ? 0.0f : (f1y + f2y + f3y) * k80;
    outs[t] = r;
    __syncthreads();

    // coalesced store: out row = 24 floats = 6 float4; block region = 256*6 float4.
    // cols 4..23 (dudt) are zero; masked rows fully zero (r already zeroed).
    float4* o4 = reinterpret_cast<float4*>(out);
    const size_t base = (size_t)blockIdx.x * BLK * (OCOLS / 4);
    const float4 z = make_float4(0.0f, 0.0f, 0.0f, 0.0f);
#pragma unroll
    for (int i = 0; i < OCOLS / 4; ++i) {
        int idx = t + i * BLK;           // 0 .. 1535
        int rr = idx / (OCOLS / 4);      // row within block
        int cc = idx - rr * (OCOLS / 4); // float4-col 0..5
        o4[base + idx] = (cc == 0) ? outs[rr] : z;
    }
}

extern "C" void kernel_launch(void* const* d_in, const int* in_sizes, int n_in,
                              void* d_out, int out_size, void* d_ws, size_t ws_size,
                              hipStream_t stream) {
    // locate y robustly: the only large input (N*44 floats); weights follow in dict order
    int iy = 1;
    for (int i = 0; i < n_in; ++i) {
        if (in_sizes[i] == NROW * YCOLS) { iy = i; break; }
    }
    const float* y   = (const float*)d_in[iy];
    const float* w1a = (const float*)d_in[iy + 1];
    const float* b1a = (const float*)d_in[iy + 2];
    const float* w1b = (const float*)d_in[iy + 3];
    const float* b1b = (const float*)d_in[iy + 4];
    const float* w2a = (const float*)d_in[iy + 5];
    const float* b2a = (const float*)d_in[iy + 6];
    const float* w2b = (const float*)d_in[iy + 7];
    const float* b2b = (const float*)d_in[iy + 8];
    const float* w2c = (const float*)d_in[iy + 9];
    const float* b2c = (const float*)d_in[iy + 10];
    const float* w3a = (const float*)d_in[iy + 11];
    const float* b3a = (const float*)d_in[iy + 12];
    const float* w3b = (const float*)d_in[iy + 13];
    const float* b3b = (const float*)d_in[iy + 14];
    const float* w3c = (const float*)d_in[iy + 15];
    const float* b3c = (const float*)d_in[iy + 16];
    float* out = (float*)d_out;

    dim3 grid(NROW / BLK), block(BLK);
    hipLaunchKernelGGL(odefunc_kernel, grid, block, 0, stream,
                       y, w1a, b1a, w1b, b1b, w2a, b2a, w2b, b2b, w2c, b2c,
                       w3a, b3a, w3b, b3b, w3c, b3c, out);
}

// Round 3
// 35.609 us; speedup vs baseline: 1.5101x; 1.5101x over previous
//
#include <hip/hip_runtime.h>
#include <stdint.h>

#define NROW  524288
#define BLK   256
#define NKNN  10
#define YCOLS 44
#define OCOLS 24     // dxdt(2) + dvdt(2) + dudt(20)

#define TBL   4096
#define T2_LO (-2.0f)
#define T3_LO (0.0f)
#define T_H   (1.0f / 256.0f)     // (hi-lo)/TBL = 16/4096
#define T_INVH 256.0f
// ws layout (floats): [0..4095]=table2 (wall MLP), [4096..8191]=table3 (neighbor MLP), [8192]=o(100)
#define WS_T2  0
#define WS_T3  4096
#define WS_O100 8192

// exact scalar -> 16 -> 8 -> 1 MLP from global weights (uniform addrs -> s_load)
__device__ __forceinline__ float mlp_scalar_g(float s,
    const float* __restrict__ wa, const float* __restrict__ ba,
    const float* __restrict__ wb, const float* __restrict__ bb,
    const float* __restrict__ wc, const float* __restrict__ bc) {
    float h[16];
#pragma unroll
    for (int j = 0; j < 16; ++j)
        h[j] = fmaxf(fmaf(s, wa[j], ba[j]), 0.0f);
    float g[8];
#pragma unroll
    for (int k = 0; k < 8; ++k) g[k] = bb[k];
#pragma unroll
    for (int j = 0; j < 16; ++j) {
        float hj = h[j];
#pragma unroll
        for (int k = 0; k < 8; ++k)
            g[k] = fmaf(hj, wb[j * 8 + k], g[k]);
    }
    float o = bc[0];
#pragma unroll
    for (int k = 0; k < 8; ++k)
        o = fmaf(fmaxf(g[k], 0.0f), wc[k], o);
    return o;
}

// ---- setup kernel: tabulate the two scalar MLPs into ws ----
__global__ __launch_bounds__(BLK) void table_kernel(
    const float* __restrict__ w2a, const float* __restrict__ b2a,
    const float* __restrict__ w2b, const float* __restrict__ b2b,
    const float* __restrict__ w2c, const float* __restrict__ b2c,
    const float* __restrict__ w3a, const float* __restrict__ b3a,
    const float* __restrict__ w3b, const float* __restrict__ b3b,
    const float* __restrict__ w3c, const float* __restrict__ b3c,
    float* __restrict__ ws)
{
    int g = blockIdx.x * BLK + threadIdx.x;
    if (g < TBL) {
        float s = T2_LO + (float)g * T_H;
        ws[WS_T2 + g] = mlp_scalar_g(s, w2a, b2a, w2b, b2b, w2c, b2c);
    } else if (g < 2 * TBL) {
        int i = g - TBL;
        float s = T3_LO + (float)i * T_H;
        ws[WS_T3 + i] = mlp_scalar_g(s, w3a, b3a, w3b, b3b, w3c, b3c);
    } else if (g == 2 * TBL) {
        ws[WS_O100] = mlp_scalar_g(100.0f, w2a, b2a, w2b, b2b, w2c, b2c);
    }
}

__device__ __forceinline__ float tbl_eval(const float* __restrict__ T, float s, float lo) {
    float u = (s - lo) * T_INVH;
    u = fminf(fmaxf(u, 0.0f), (float)(TBL - 1) - 0.001f);
    int i = (int)u;
    float f = u - (float)i;
    float a = T[i];
    float b = T[i + 1];
    return fmaf(f, b - a, a);
}

// ---- main kernel ----
__global__ __launch_bounds__(BLK) void odefunc_kernel(
    const float* __restrict__ y,
    const float* __restrict__ w1a, const float* __restrict__ b1a,
    const float* __restrict__ w1b, const float* __restrict__ b1b,
    const float* __restrict__ ws,
    float* __restrict__ out)
{
    __shared__ float T2[TBL];
    __shared__ float T3[TBL];
    __shared__ float4 outs[BLK];

    const int t = threadIdx.x;
    // stage tables: 1024 float4 each, 4 per thread
    {
        const float4* g2 = reinterpret_cast<const float4*>(ws + WS_T2);
        const float4* g3 = reinterpret_cast<const float4*>(ws + WS_T3);
        float4* l2 = reinterpret_cast<float4*>(T2);
        float4* l3 = reinterpret_cast<float4*>(T3);
#pragma unroll
        for (int k = 0; k < TBL / 4 / BLK; ++k) {
            l2[t + k * BLK] = g2[t + k * BLK];
            l3[t + k * BLK] = g3[t + k * BLK];
        }
    }
    const float o100 = ws[WS_O100];   // uniform scalar load
    __syncthreads();

    const int row = blockIdx.x * BLK + t;
    // y row = 44 floats = 176 B = 11 * 16 B -> 16B-aligned row starts
    const float4* yr = reinterpret_cast<const float4*>(y + (size_t)row * YCOLS);
    float4 a  = yr[0];            // x0, x1, vx, vy
    float4 u0 = yr[1];
    float4 u1 = yr[2];
    float4 u2 = yr[3];
    float4 u3 = yr[4];
    float4 u4 = yr[5];            // cols 4..23 = ux[10][2]

    // ---- f1: door-direction MLP (4 -> 8 -> 2), weights via uniform s_loads ----
    float dx = 5.6f - a.x;
    float dy = 0.0f - a.y;
    float inv = rsqrtf(fmaf(dx, dx, dy * dy));
    float in1[4] = { dx * inv, dy * inv, a.z, a.w };
    float h1[8];
#pragma unroll
    for (int j = 0; j < 8; ++j) {
        float s = b1a[j];
#pragma unroll
        for (int k = 0; k < 4; ++k)
            s = fmaf(in1[k], w1a[k * 8 + j], s);
        h1[j] = fmaxf(s, 0.0f);
    }
    float f1x = b1b[0];
    float f1y = b1b[1];
#pragma unroll
    for (int j = 0; j < 8; ++j) {
        f1x = fmaf(h1[j], w1b[j * 2 + 0], f1x);
        f1y = fmaf(h1[j], w1b[j * 2 + 1], f1y);
    }

    // ---- f2: wall MLP via table ----
    bool corridor = (a.y < 1.0f) && (a.y > -1.0f);
    float o0 = tbl_eval(T2, a.x + 5.0f, T2_LO);
    float o1 = tbl_eval(T2, a.y + 5.0f, T2_LO);
    float o2 = tbl_eval(T2, 5.0f - a.y, T2_LO);
    float o3 = corridor ? o100 : tbl_eval(T2, 5.0f - a.x, T2_LO);
    float f2x = o0 - o3;
    float f2y = o1 - o2;

    // ---- f3: neighbor MLP via table ----
    float us[2 * NKNN] = { u0.x, u0.y, u0.z, u0.w,
                           u1.x, u1.y, u1.z, u1.w,
                           u2.x, u2.y, u2.z, u2.w,
                           u3.x, u3.y, u3.z, u3.w,
                           u4.x, u4.y, u4.z, u4.w };
    float f3x = 0.0f, f3y = 0.0f;
#pragma unroll
    for (int n = 0; n < NKNN; ++n) {
        float uxn = us[2 * n + 0];
        float uyn = us[2 * n + 1];
        float s2  = fmaf(uxn, uxn, uyn * uyn);
        float idn = rsqrtf(s2);
        float d   = s2 * idn;     // = sqrt(s2)
        float m   = tbl_eval(T3, d, T3_LO);
        float c   = m * idn;
        f3x = fmaf(-c, uxn, f3x);
        f3y = fmaf(-c, uyn, f3y);
    }

    // ---- combine + mask ----
    bool dead = (a.x > 5.0f);
    const float k80 = 1.0f / 80.0f;
    float4 r;
    r.x = dead ? 0.0f : a.z;
    r.y = dead ? 0.0f : a.w;
    r.z = dead ? 0.0f : (f1x + f2x + f3x) * k80;
    r.w = dead ? 0.0f : (f1y + f2y + f3y) * k80;
    outs[t] = r;
    __syncthreads();

    // coalesced store: out row = 24 floats = 6 float4; block region = 256*6 float4
    float4* o4 = reinterpret_cast<float4*>(out);
    const size_t base = (size_t)blockIdx.x * BLK * (OCOLS / 4);
    const float4 z = make_float4(0.0f, 0.0f, 0.0f, 0.0f);
#pragma unroll
    for (int i = 0; i < OCOLS / 4; ++i) {
        int idx = t + i * BLK;
        int rr = idx / (OCOLS / 4);
        int cc = idx - rr * (OCOLS / 4);
        o4[base + idx] = (cc == 0) ? outs[rr] : z;
    }
}

extern "C" void kernel_launch(void* const* d_in, const int* in_sizes, int n_in,
                              void* d_out, int out_size, void* d_ws, size_t ws_size,
                              hipStream_t stream) {
    int iy = 1;
    for (int i = 0; i < n_in; ++i) {
        if (in_sizes[i] == NROW * YCOLS) { iy = i; break; }
    }
    const float* y   = (const float*)d_in[iy];
    const float* w1a = (const float*)d_in[iy + 1];
    const float* b1a = (const float*)d_in[iy + 2];
    const float* w1b = (const float*)d_in[iy + 3];
    const float* b1b = (const float*)d_in[iy + 4];
    const float* w2a = (const float*)d_in[iy + 5];
    const float* b2a = (const float*)d_in[iy + 6];
    const float* w2b = (const float*)d_in[iy + 7];
    const float* b2b = (const float*)d_in[iy + 8];
    const float* w2c = (const float*)d_in[iy + 9];
    const float* b2c = (const float*)d_in[iy + 10];
    const float* w3a = (const float*)d_in[iy + 11];
    const float* b3a = (const float*)d_in[iy + 12];
    const float* w3b = (const float*)d_in[iy + 13];
    const float* b3b = (const float*)d_in[iy + 14];
    const float* w3c = (const float*)d_in[iy + 15];
    const float* b3c = (const float*)d_in[iy + 16];
    float* out = (float*)d_out;
    float* ws  = (float*)d_ws;

    // 1) tabulate the two scalar MLPs (8193 entries)
    hipLaunchKernelGGL(table_kernel, dim3((2 * TBL + BLK) / BLK + 1), dim3(BLK), 0, stream,
                       w2a, b2a, w2b, b2b, w2c, b2c,
                       w3a, b3a, w3b, b3b, w3c, b3c, ws);
    // 2) main pass
    hipLaunchKernelGGL(odefunc_kernel, dim3(NROW / BLK), dim3(BLK), 0, stream,
                       y, w1a, b1a, w1b, b1b, ws, out);
}

// Round 4
// 34.538 us; speedup vs baseline: 1.5569x; 1.0310x over previous
//
#include <hip/hip_runtime.h>
#include <stdint.h>

#define NROW  524288
#define BLK   256
#define NKNN  10
#define YCOLS 44
#define OCOLS 24     // dxdt(2) + dvdt(2) + dudt(20)

#define TBL    1024
#define T2_LO  (-2.0f)
#define T3_LO  (0.0f)
#define T_H    (1.0f / 64.0f)     // span 16 over 1024 entries
#define T_INVH 64.0f
// ws layout (floats): [0..2047] = T2 pairs (val,slope), [2048..4095] = T3 pairs, [4096] = o(100)
#define WS_T2   0
#define WS_T3   (2 * TBL)
#define WS_O100 (4 * TBL)

// exact scalar -> 16 -> 8 -> 1 MLP from global weights
__device__ __forceinline__ float mlp_scalar_g(float s,
    const float* __restrict__ wa, const float* __restrict__ ba,
    const float* __restrict__ wb, const float* __restrict__ bb,
    const float* __restrict__ wc, const float* __restrict__ bc) {
    float h[16];
#pragma unroll
    for (int j = 0; j < 16; ++j)
        h[j] = fmaxf(fmaf(s, wa[j], ba[j]), 0.0f);
    float g[8];
#pragma unroll
    for (int k = 0; k < 8; ++k) g[k] = bb[k];
#pragma unroll
    for (int j = 0; j < 16; ++j) {
        float hj = h[j];
#pragma unroll
        for (int k = 0; k < 8; ++k)
            g[k] = fmaf(hj, wb[j * 8 + k], g[k]);
    }
    float o = bc[0];
#pragma unroll
    for (int k = 0; k < 8; ++k)
        o = fmaf(fmaxf(g[k], 0.0f), wc[k], o);
    return o;
}

// ---- setup kernel: tabulate (value, slope) pairs for the two scalar MLPs ----
__global__ __launch_bounds__(BLK) void table_kernel(
    const float* __restrict__ w2a, const float* __restrict__ b2a,
    const float* __restrict__ w2b, const float* __restrict__ b2b,
    const float* __restrict__ w2c, const float* __restrict__ b2c,
    const float* __restrict__ w3a, const float* __restrict__ b3a,
    const float* __restrict__ w3b, const float* __restrict__ b3b,
    const float* __restrict__ w3c, const float* __restrict__ b3c,
    float* __restrict__ ws)
{
    int g = blockIdx.x * BLK + threadIdx.x;
    if (g < TBL) {
        float s  = T2_LO + (float)g * T_H;
        float v0 = mlp_scalar_g(s,       w2a, b2a, w2b, b2b, w2c, b2c);
        float v1 = mlp_scalar_g(s + T_H, w2a, b2a, w2b, b2b, w2c, b2c);
        ws[WS_T2 + 2 * g + 0] = v0;
        ws[WS_T2 + 2 * g + 1] = v1 - v0;
    } else if (g < 2 * TBL) {
        int i = g - TBL;
        float s  = T3_LO + (float)i * T_H;
        float v0 = mlp_scalar_g(s,       w3a, b3a, w3b, b3b, w3c, b3c);
        float v1 = mlp_scalar_g(s + T_H, w3a, b3a, w3b, b3b, w3c, b3c);
        ws[WS_T3 + 2 * i + 0] = v0;
        ws[WS_T3 + 2 * i + 1] = v1 - v0;
    } else if (g == 2 * TBL) {
        ws[WS_O100] = mlp_scalar_g(100.0f, w2a, b2a, w2b, b2b, w2c, b2c);
    }
}

__device__ __forceinline__ float tbl_eval(const float2* __restrict__ T, float s, float lo) {
    float u = (s - lo) * T_INVH;
    u = fminf(fmaxf(u, 0.0f), (float)TBL - 1.001f);
    int i = (int)u;
    float f = u - (float)i;
    float2 e = T[i];               // one ds_read_b64
    return fmaf(f, e.y, e.x);
}

// ---- main kernel ----
__global__ __launch_bounds__(BLK) void odefunc_kernel(
    const float* __restrict__ y,
    const float* __restrict__ w1a, const float* __restrict__ b1a,
    const float* __restrict__ w1b, const float* __restrict__ b1b,
    const float* __restrict__ ws,
    float* __restrict__ out)
{
    __shared__ float2 T2[TBL];     // 8 KB
    __shared__ float2 T3[TBL];     // 8 KB
    __shared__ float4 outs[BLK];   // 4 KB   -> 20 KB total, 8 blocks/CU

    const int t = threadIdx.x;
    const int row = blockIdx.x * BLK + t;

    // issue row loads FIRST so HBM latency hides under table staging
    const float4* yr = reinterpret_cast<const float4*>(y + (size_t)row * YCOLS);
    float4 a  = yr[0];            // x0, x1, vx, vy
    float4 u0 = yr[1];
    float4 u1 = yr[2];
    float4 u2 = yr[3];
    float4 u3 = yr[4];
    float4 u4 = yr[5];            // cols 4..23 = ux[10][2]

    // stage tables: 4096 floats = 1024 float4, 4 per thread
    {
        const float4* g4 = reinterpret_cast<const float4*>(ws);
        float4* l2 = reinterpret_cast<float4*>(T2);  // first 512 float4
        float4* l3 = reinterpret_cast<float4*>(T3);  // next 512 float4
        float4 v0 = g4[t];
        float4 v1 = g4[t + 256];
        float4 v2 = g4[t + 512];
        float4 v3 = g4[t + 768];
        l2[t]       = v0;
        l2[t + 256] = v1;
        l3[t]       = v2;
        l3[t + 256] = v3;
    }
    const float o100 = ws[WS_O100];   // uniform scalar load
    __syncthreads();

    // ---- f1: door-direction MLP (4 -> 8 -> 2), weights via uniform s_loads ----
    float dx = 5.6f - a.x;
    float dy = 0.0f - a.y;
    float inv = rsqrtf(fmaf(dx, dx, dy * dy));
    float in1[4] = { dx * inv, dy * inv, a.z, a.w };
    float h1[8];
#pragma unroll
    for (int j = 0; j < 8; ++j) {
        float s = b1a[j];
#pragma unroll
        for (int k = 0; k < 4; ++k)
            s = fmaf(in1[k], w1a[k * 8 + j], s);
        h1[j] = fmaxf(s, 0.0f);
    }
    float f1x = b1b[0];
    float f1y = b1b[1];
#pragma unroll
    for (int j = 0; j < 8; ++j) {
        f1x = fmaf(h1[j], w1b[j * 2 + 0], f1x);
        f1y = fmaf(h1[j], w1b[j * 2 + 1], f1y);
    }

    // ---- f2: wall MLP via table ----
    bool corridor = (a.y < 1.0f) && (a.y > -1.0f);
    float o0 = tbl_eval(T2, a.x + 5.0f, T2_LO);
    float o1 = tbl_eval(T2, a.y + 5.0f, T2_LO);
    float o2 = tbl_eval(T2, 5.0f - a.y, T2_LO);
    float o3 = corridor ? o100 : tbl_eval(T2, 5.0f - a.x, T2_LO);
    float f2x = o0 - o3;
    float f2y = o1 - o2;

    // ---- f3: neighbor MLP via table ----
    float us[2 * NKNN] = { u0.x, u0.y, u0.z, u0.w,
                           u1.x, u1.y, u1.z, u1.w,
                           u2.x, u2.y, u2.z, u2.w,
                           u3.x, u3.y, u3.z, u3.w,
                           u4.x, u4.y, u4.z, u4.w };
    float f3x = 0.0f, f3y = 0.0f;
#pragma unroll
    for (int n = 0; n < NKNN; ++n) {
        float uxn = us[2 * n + 0];
        float uyn = us[2 * n + 1];
        float s2  = fmaf(uxn, uxn, uyn * uyn);
        float idn = rsqrtf(s2);
        float d   = s2 * idn;     // = sqrt(s2)
        float m   = tbl_eval(T3, d, T3_LO);
        float c   = m * idn;
        f3x = fmaf(-c, uxn, f3x);
        f3y = fmaf(-c, uyn, f3y);
    }

    // ---- combine + mask ----
    bool dead = (a.x > 5.0f);
    const float k80 = 1.0f / 80.0f;
    float4 r;
    r.x = dead ? 0.0f : a.z;
    r.y = dead ? 0.0f : a.w;
    r.z = dead ? 0.0f : (f1x + f2x + f3x) * k80;
    r.w = dead ? 0.0f : (f1y + f2y + f3y) * k80;
    outs[t] = r;
    __syncthreads();

    // coalesced store: out row = 24 floats = 6 float4; block region = 256*6 float4
    float4* o4 = reinterpret_cast<float4*>(out);
    const size_t base = (size_t)blockIdx.x * BLK * (OCOLS / 4);
    const float4 z = make_float4(0.0f, 0.0f, 0.0f, 0.0f);
#pragma unroll
    for (int i = 0; i < OCOLS / 4; ++i) {
        int idx = t + i * BLK;
        int rr = idx / (OCOLS / 4);
        int cc = idx - rr * (OCOLS / 4);
        o4[base + idx] = (cc == 0) ? outs[rr] : z;
    }
}

extern "C" void kernel_launch(void* const* d_in, const int* in_sizes, int n_in,
                              void* d_out, int out_size, void* d_ws, size_t ws_size,
                              hipStream_t stream) {
    int iy = 1;
    for (int i = 0; i < n_in; ++i) {
        if (in_sizes[i] == NROW * YCOLS) { iy = i; break; }
    }
    const float* y   = (const float*)d_in[iy];
    const float* w1a = (const float*)d_in[iy + 1];
    const float* b1a = (const float*)d_in[iy + 2];
    const float* w1b = (const float*)d_in[iy + 3];
    const float* b1b = (const float*)d_in[iy + 4];
    const float* w2a = (const float*)d_in[iy + 5];
    const float* b2a = (const float*)d_in[iy + 6];
    const float* w2b = (const float*)d_in[iy + 7];
    const float* b2b = (const float*)d_in[iy + 8];
    const float* w2c = (const float*)d_in[iy + 9];
    const float* b2c = (const float*)d_in[iy + 10];
    const float* w3a = (const float*)d_in[iy + 11];
    const float* b3a = (const float*)d_in[iy + 12];
    const float* w3b = (const float*)d_in[iy + 13];
    const float* b3b = (const float*)d_in[iy + 14];
    const float* w3c = (const float*)d_in[iy + 15];
    const float* b3c = (const float*)d_in[iy + 16];
    float* out = (float*)d_out;
    float* ws  = (float*)d_ws;

    // 1) tabulate (val, slope) pairs (2*1024 entries + o(100))
    hipLaunchKernelGGL(table_kernel, dim3((2 * TBL) / BLK + 1), dim3(BLK), 0, stream,
                       w2a, b2a, w2b, b2b, w2c, b2c,
                       w3a, b3a, w3b, b3b, w3c, b3c, ws);
    // 2) main pass
    hipLaunchKernelGGL(odefunc_kernel, dim3(NROW / BLK), dim3(BLK), 0, stream,
                       y, w1a, b1a, w1b, b1b, ws, out);
}